// Round 3
// baseline (2001.061 us; speedup 1.0000x reference)
//
#include <hip/hip_runtime.h>

#define EMB  1024
#define NH   16
#define NKV  4
#define HD   128
#define NEXP 8
#define MOEH 1024
#define BB   2
#define SS   2048
#define TT   (BB*SS)      // 4096 tokens
#define QKVN 3072
#define ATT_SCALE 0.08838834764831845f  // 1/sqrt(128)

typedef unsigned short u16;
typedef unsigned int   u32;
typedef __bf16  bf16x8  __attribute__((ext_vector_type(8)));
typedef float   floatx4 __attribute__((ext_vector_type(4)));

__device__ __forceinline__ u16 f2b(float f){           // f32 -> bf16 RNE
    u32 u = __float_as_uint(f);
    u = u + 0x7fffu + ((u >> 16) & 1u);
    return (u16)(u >> 16);
}
__device__ __forceinline__ float b2f(u16 h){
    return __uint_as_float(((u32)h) << 16);
}
__device__ __forceinline__ void split2(float v, u16& hi, u16& lo){
    u16 h = f2b(v);
    hi = h;
    lo = f2b(v - b2f(h));
}

// ---------------- weight converts ----------------
__global__ void k_cvt(const float* __restrict__ src, u16* __restrict__ dst, int n){
    int i = (blockIdx.x * blockDim.x + threadIdx.x) * 4;
    if (i < n){
        float4 v = *(const float4*)(src + i);
        ushort4 o;
        o.x = f2b(v.x); o.y = f2b(v.y); o.z = f2b(v.z); o.w = f2b(v.w);
        *(ushort4*)(dst + i) = o;
    }
}
__global__ void k_cvt_split(const float* __restrict__ src, u16* __restrict__ dh,
                            u16* __restrict__ dl, int n){
    int i = (blockIdx.x * blockDim.x + threadIdx.x) * 4;
    if (i < n){
        float4 v = *(const float4*)(src + i);
        ushort4 oh, ol;
        split2(v.x, oh.x, ol.x); split2(v.y, oh.y, ol.y);
        split2(v.z, oh.z, ol.z); split2(v.w, oh.w, ol.w);
        *(ushort4*)(dh + i) = oh;
        *(ushort4*)(dl + i) = ol;
    }
}

// ---------------- rmsnorm variants ----------------
__global__ void k_rmsnorm_split(const float* __restrict__ x, const float* __restrict__ w,
                                u16* __restrict__ oh, u16* __restrict__ ol){
    int t   = blockIdx.x;
    int tid = threadIdx.x;
    const float* xr = x + (size_t)t * EMB;
    float4 v = *(const float4*)(xr + tid * 4);
    float ss = v.x*v.x + v.y*v.y + v.z*v.z + v.w*v.w;
    #pragma unroll
    for (int m = 32; m; m >>= 1) ss += __shfl_xor(ss, m);
    __shared__ float sred[4];
    if ((tid & 63) == 0) sred[tid >> 6] = ss;
    __syncthreads();
    float tot = sred[0] + sred[1] + sred[2] + sred[3];
    float r = rsqrtf(tot * (1.0f / EMB) + 1e-6f);
    float4 wv = *(const float4*)(w + tid * 4);
    ushort4 h4, l4;
    split2(v.x * r * wv.x, h4.x, l4.x);
    split2(v.y * r * wv.y, h4.y, l4.y);
    split2(v.z * r * wv.z, h4.z, l4.z);
    split2(v.w * r * wv.w, h4.w, l4.w);
    *(ushort4*)(oh + (size_t)t * EMB + tid * 4) = h4;
    *(ushort4*)(ol + (size_t)t * EMB + tid * 4) = l4;
}

__global__ void k_rmsnorm_dual(const float* __restrict__ x, const float* __restrict__ w,
                               float* __restrict__ of, u16* __restrict__ oh){
    int t   = blockIdx.x;
    int tid = threadIdx.x;
    const float* xr = x + (size_t)t * EMB;
    float4 v = *(const float4*)(xr + tid * 4);
    float ss = v.x*v.x + v.y*v.y + v.z*v.z + v.w*v.w;
    #pragma unroll
    for (int m = 32; m; m >>= 1) ss += __shfl_xor(ss, m);
    __shared__ float sred[4];
    if ((tid & 63) == 0) sred[tid >> 6] = ss;
    __syncthreads();
    float tot = sred[0] + sred[1] + sred[2] + sred[3];
    float r = rsqrtf(tot * (1.0f / EMB) + 1e-6f);
    float4 wv = *(const float4*)(w + tid * 4);
    float4 o;
    o.x = v.x * r * wv.x; o.y = v.y * r * wv.y;
    o.z = v.z * r * wv.z; o.w = v.w * r * wv.w;
    *(float4*)(of + (size_t)t * EMB + tid * 4) = o;
    ushort4 h4;
    h4.x = f2b(o.x); h4.y = f2b(o.y); h4.z = f2b(o.z); h4.w = f2b(o.w);
    *(ushort4*)(oh + (size_t)t * EMB + tid * 4) = h4;
}

// ---------------- plain bf16 MFMA 64x64 wave tile core ----------------
__device__ __forceinline__ void gemm_core(const u16* const* a, const u16* const* b,
                                          int K, floatx4 acc[4][4]){
    for (int k0 = 0; k0 < K; k0 += 32){
        bf16x8 fa[4], fb[4];
        #pragma unroll
        for (int i = 0; i < 4; i++){
            fa[i] = *(const bf16x8*)(a[i] + k0);
            fb[i] = *(const bf16x8*)(b[i] + k0);
        }
        #pragma unroll
        for (int i = 0; i < 4; i++)
            #pragma unroll
            for (int j = 0; j < 4; j++)
                acc[i][j] = __builtin_amdgcn_mfma_f32_16x16x32_bf16(fa[i], fb[j], acc[i][j], 0, 0, 0);
    }
}

// ---------------- split (hi/lo) MFMA 64x64 wave tile core ----------------
__device__ __forceinline__ void gemm_core_split(const u16* __restrict__ ah, const u16* __restrict__ al,
                                                const u16* __restrict__ bh, const u16* __restrict__ bl,
                                                const size_t* aoff, const size_t* boff,
                                                int K, floatx4 acc[4][4]){
    for (int k0 = 0; k0 < K; k0 += 32){
        bf16x8 fah[4], fal[4], fbh[4], fbl[4];
        #pragma unroll
        for (int i = 0; i < 4; i++){
            fah[i] = *(const bf16x8*)(ah + aoff[i] + k0);
            fal[i] = *(const bf16x8*)(al + aoff[i] + k0);
            fbh[i] = *(const bf16x8*)(bh + boff[i] + k0);
            fbl[i] = *(const bf16x8*)(bl + boff[i] + k0);
        }
        #pragma unroll
        for (int i = 0; i < 4; i++)
            #pragma unroll
            for (int j = 0; j < 4; j++){
                acc[i][j] = __builtin_amdgcn_mfma_f32_16x16x32_bf16(fal[i], fbh[j], acc[i][j], 0, 0, 0);
                acc[i][j] = __builtin_amdgcn_mfma_f32_16x16x32_bf16(fah[i], fbl[j], acc[i][j], 0, 0, 0);
                acc[i][j] = __builtin_amdgcn_mfma_f32_16x16x32_bf16(fah[i], fbh[j], acc[i][j], 0, 0, 0);
            }
    }
}

// QKV (split): C[TT x 3072] fp32 = h1 @ Wqkv^T
__global__ void k_gemm_qkv(const u16* __restrict__ Ah, const u16* __restrict__ Al,
                           const u16* __restrict__ Bh, const u16* __restrict__ Bl,
                           float* __restrict__ C){
    int lane = threadIdx.x;
    int m16 = lane & 15, quad = lane >> 4;
    int row0 = blockIdx.y * 64, col0 = blockIdx.x * 64;
    size_t aoff[4], boff[4];
    #pragma unroll
    for (int i = 0; i < 4; i++){
        aoff[i] = (size_t)(row0 + 16*i + m16) * EMB + quad*8;
        boff[i] = (size_t)(col0 + 16*i + m16) * EMB + quad*8;
    }
    floatx4 acc[4][4];
    floatx4 z = {0.f,0.f,0.f,0.f};
    #pragma unroll
    for (int i=0;i<4;i++) for (int j=0;j<4;j++) acc[i][j] = z;
    gemm_core_split(Ah, Al, Bh, Bl, aoff, boff, EMB, acc);
    #pragma unroll
    for (int i = 0; i < 4; i++)
        #pragma unroll
        for (int j = 0; j < 4; j++)
            #pragma unroll
            for (int r = 0; r < 4; r++){
                int row = row0 + 16*i + quad*4 + r;
                int col = col0 + 16*j + m16;
                C[(size_t)row * QKVN + col] = acc[i][j][r];
            }
}

// O-proj (split): xattn[TT x 1024] f32 = ctx @ o_w^T + x
__global__ void k_gemm_o(const u16* __restrict__ Ah, const u16* __restrict__ Al,
                         const u16* __restrict__ Bh, const u16* __restrict__ Bl,
                         const float* __restrict__ resid, float* __restrict__ C){
    int lane = threadIdx.x;
    int m16 = lane & 15, quad = lane >> 4;
    int row0 = blockIdx.y * 64, col0 = blockIdx.x * 64;
    size_t aoff[4], boff[4];
    #pragma unroll
    for (int i = 0; i < 4; i++){
        aoff[i] = (size_t)(row0 + 16*i + m16) * 2048 + quad*8;
        boff[i] = (size_t)(col0 + 16*i + m16) * 2048 + quad*8;
    }
    floatx4 acc[4][4];
    floatx4 z = {0.f,0.f,0.f,0.f};
    #pragma unroll
    for (int i=0;i<4;i++) for (int j=0;j<4;j++) acc[i][j] = z;
    gemm_core_split(Ah, Al, Bh, Bl, aoff, boff, 2048, acc);
    #pragma unroll
    for (int i = 0; i < 4; i++)
        #pragma unroll
        for (int j = 0; j < 4; j++)
            #pragma unroll
            for (int r = 0; r < 4; r++){
                int row = row0 + 16*i + quad*4 + r;
                int col = col0 + 16*j + m16;
                C[(size_t)row * EMB + col] = acc[i][j][r] + resid[(size_t)row * EMB + col];
            }
}

// gate_up (plain bf16): compact GU[8192 x 2048]
__global__ void k_gemm_gu(const u16* __restrict__ H2, const u16* __restrict__ WGU,
                          const int* __restrict__ list, const int* __restrict__ offs,
                          u16* __restrict__ GU){
    int e = blockIdx.z;
    int off = offs[e];
    int cnt = offs[e+1] - off;
    int row0 = blockIdx.y * 64;
    if (row0 >= cnt) return;
    int col0 = blockIdx.x * 64;
    int lane = threadIdx.x;
    int m16 = lane & 15, quad = lane >> 4;
    const u16* a[4]; const u16* b[4];
    #pragma unroll
    for (int i = 0; i < 4; i++){
        int rl = row0 + 16*i + m16;
        rl = rl < cnt ? rl : cnt - 1;
        int tok = list[off + rl];
        a[i] = H2 + (size_t)tok * EMB + quad*8;
        b[i] = WGU + ((size_t)e * 2048 + col0 + 16*i + m16) * EMB + quad*8;
    }
    floatx4 acc[4][4];
    floatx4 z = {0.f,0.f,0.f,0.f};
    #pragma unroll
    for (int i=0;i<4;i++) for (int j=0;j<4;j++) acc[i][j] = z;
    gemm_core(a, b, EMB, acc);
    #pragma unroll
    for (int i = 0; i < 4; i++)
        #pragma unroll
        for (int j = 0; j < 4; j++)
            #pragma unroll
            for (int r = 0; r < 4; r++){
                int rl = row0 + 16*i + quad*4 + r;
                if (rl < cnt){
                    int col = col0 + 16*j + m16;
                    GU[(size_t)(off + rl) * 2048 + col] = f2b(acc[i][j][r]);
                }
            }
}

// down (plain bf16): compact YD[8192 x 1024]
__global__ void k_gemm_down(const u16* __restrict__ ACT, const u16* __restrict__ WD,
                            const int* __restrict__ offs, u16* __restrict__ YD){
    int e = blockIdx.z;
    int off = offs[e];
    int cnt = offs[e+1] - off;
    int row0 = blockIdx.y * 64;
    if (row0 >= cnt) return;
    int col0 = blockIdx.x * 64;
    int lane = threadIdx.x;
    int m16 = lane & 15, quad = lane >> 4;
    const u16* a[4]; const u16* b[4];
    #pragma unroll
    for (int i = 0; i < 4; i++){
        int rl = row0 + 16*i + m16;
        rl = rl < cnt ? rl : cnt - 1;
        a[i] = ACT + (size_t)(off + rl) * MOEH + quad*8;
        b[i] = WD + ((size_t)e * 1024 + col0 + 16*i + m16) * MOEH + quad*8;
    }
    floatx4 acc[4][4];
    floatx4 z = {0.f,0.f,0.f,0.f};
    #pragma unroll
    for (int i=0;i<4;i++) for (int j=0;j<4;j++) acc[i][j] = z;
    gemm_core(a, b, MOEH, acc);
    #pragma unroll
    for (int i = 0; i < 4; i++)
        #pragma unroll
        for (int j = 0; j < 4; j++)
            #pragma unroll
            for (int r = 0; r < 4; r++){
                int rl = row0 + 16*i + quad*4 + r;
                if (rl < cnt){
                    int col = col0 + 16*j + m16;
                    YD[(size_t)(off + rl) * 1024 + col] = f2b(acc[i][j][r]);
                }
            }
}

// ---------------- per-head QK rmsnorm + RoPE (fp32 in, split out) ----------------
__global__ void k_qknorm_rope(const float* __restrict__ QKVF,
                              const float* __restrict__ qnw, const float* __restrict__ knw,
                              const int* __restrict__ posids,
                              u16* __restrict__ Qh, u16* __restrict__ Ql,
                              u16* __restrict__ Kh, u16* __restrict__ Kl,
                              u16* __restrict__ Vth, u16* __restrict__ Vtl){
    int t = blockIdx.x;
    int b = t >> 11, s = t & 2047;
    int wave = threadIdx.x >> 6, lane = threadIdx.x & 63;
    const float* row = QKVF + (size_t)t * QKVN;
    float pos = (float)posids[s];
    float invf = powf(10000.0f, -((float)lane) * (1.0f/64.0f));
    float fr = pos * invf;
    float sn, cs;
    sincosf(fr, &sn, &cs);
    for (int slot = wave; slot < 24; slot += 4){
        if (slot < 16){                                 // Q head
            const float* src = row + slot * HD;
            float x1 = src[lane], x2 = src[lane + 64];
            float ssq = x1*x1 + x2*x2;
            #pragma unroll
            for (int m = 32; m; m >>= 1) ssq += __shfl_xor(ssq, m);
            float r = rsqrtf(ssq * (1.0f/HD) + 1e-6f);
            float q1 = x1 * r * qnw[lane], q2 = x2 * r * qnw[lane + 64];
            float o1 = q1*cs - q2*sn, o2 = q2*cs + q1*sn;
            size_t base = ((size_t)(b*NH + slot) * SS + s) * HD;
            u16 h, l;
            split2(o1, h, l); Qh[base + lane] = h;      Ql[base + lane] = l;
            split2(o2, h, l); Qh[base + lane + 64] = h; Ql[base + lane + 64] = l;
        } else if (slot < 20){                          // K head
            int kh = slot - 16;
            const float* src = row + 2048 + kh * HD;
            float x1 = src[lane], x2 = src[lane + 64];
            float ssq = x1*x1 + x2*x2;
            #pragma unroll
            for (int m = 32; m; m >>= 1) ssq += __shfl_xor(ssq, m);
            float r = rsqrtf(ssq * (1.0f/HD) + 1e-6f);
            float q1 = x1 * r * knw[lane], q2 = x2 * r * knw[lane + 64];
            float o1 = q1*cs - q2*sn, o2 = q2*cs + q1*sn;
            size_t base = ((size_t)(b*NKV + kh) * SS + s) * HD;
            u16 h, l;
            split2(o1, h, l); Kh[base + lane] = h;      Kl[base + lane] = l;
            split2(o2, h, l); Kh[base + lane + 64] = h; Kl[base + lane + 64] = l;
        } else {                                        // V head, transposed split copy
            int vh = slot - 20;
            const float* src = row + 2560 + vh * HD;
            size_t base = ((size_t)(b*NKV + vh) * HD) * SS + s;
            u16 h, l;
            split2(src[lane], h, l);
            Vth[base + (size_t)lane * SS] = h; Vtl[base + (size_t)lane * SS] = l;
            split2(src[lane + 64], h, l);
            Vth[base + (size_t)(lane + 64) * SS] = h; Vtl[base + (size_t)(lane + 64) * SS] = l;
        }
    }
}

// ---------------- flash attention v2: fixed-max softmax, 64-wide KV tiles ----------------
// one wave = 16 Q rows. Scores bounded: |q|=|k|=sqrt(128) (rmsnormed), RoPE is a
// rotation => |s| <= 128*scale = 11.32 < 12. p = exp(s-12): same softmax, no
// running max, no rescale, l-sum deferred to per-lane accumulation.
#define PSTRIDE 72
__global__ void k_attn(const u16* __restrict__ Qh, const u16* __restrict__ Ql,
                       const u16* __restrict__ Kh, const u16* __restrict__ Kl,
                       const u16* __restrict__ Vth, const u16* __restrict__ Vtl,
                       u16* __restrict__ ctxh, u16* __restrict__ ctxl){
    int b = blockIdx.z, h = blockIdx.y;
    int q0 = (gridDim.x - 1 - blockIdx.x) * 16;   // heavy blocks first
    int kvh = h >> 2;
    int lane = threadIdx.x;
    int m16 = lane & 15, quad = lane >> 4;
    size_t qbase = ((size_t)(b*NH + h) * SS + q0) * HD;
    size_t kbase = ((size_t)(b*NKV + kvh) * SS) * HD;
    size_t vbase = ((size_t)(b*NKV + kvh) * HD) * SS;

    bf16x8 aqh[4], aql[4];
    #pragma unroll
    for (int kk = 0; kk < 4; kk++){
        aqh[kk] = *(const bf16x8*)(Qh + qbase + (size_t)m16 * HD + kk*32 + quad*8);
        aql[kk] = *(const bf16x8*)(Ql + qbase + (size_t)m16 * HD + kk*32 + quad*8);
    }

    floatx4 z = {0.f,0.f,0.f,0.f};
    floatx4 o[8];
    #pragma unroll
    for (int j = 0; j < 8; j++) o[j] = z;
    float lrun[4] = {0.f, 0.f, 0.f, 0.f};

    __shared__ u16 pbh[16 * PSTRIDE];
    __shared__ u16 pbl[16 * PSTRIDE];

    int qmax = q0 + 15;
    for (int kv0 = 0; kv0 <= qmax; kv0 += 64){
        // scores: four 16-col kv tiles (split-precision QK^T)
        floatx4 sc[4];
        #pragma unroll
        for (int tt = 0; tt < 4; tt++){
            sc[tt] = z;
            size_t kb = kbase + (size_t)(kv0 + tt*16 + m16) * HD + quad*8;
            #pragma unroll
            for (int kk = 0; kk < 4; kk++){
                bf16x8 bkh = *(const bf16x8*)(Kh + kb + kk*32);
                bf16x8 bkl = *(const bf16x8*)(Kl + kb + kk*32);
                sc[tt] = __builtin_amdgcn_mfma_f32_16x16x32_bf16(aql[kk], bkh, sc[tt], 0, 0, 0);
                sc[tt] = __builtin_amdgcn_mfma_f32_16x16x32_bf16(aqh[kk], bkl, sc[tt], 0, 0, 0);
                sc[tt] = __builtin_amdgcn_mfma_f32_16x16x32_bf16(aqh[kk], bkh, sc[tt], 0, 0, 0);
            }
        }
        // fixed-max softmax: p = exp(s*scale - 12), causal mask, per-lane l accum
        #pragma unroll
        for (int tt = 0; tt < 4; tt++){
            int col = kv0 + tt*16 + m16;
            #pragma unroll
            for (int r = 0; r < 4; r++){
                int qpos = q0 + quad*4 + r;
                float p = (col > qpos) ? 0.0f : __expf(sc[tt][r] * ATT_SCALE - 12.0f);
                sc[tt][r] = p;
                lrun[r] += p;
            }
        }
        __syncthreads();     // prior pbuf reads done (single-wave: cheap)
        #pragma unroll
        for (int tt = 0; tt < 4; tt++)
            #pragma unroll
            for (int r = 0; r < 4; r++){
                u16 ph, pl;
                split2(sc[tt][r], ph, pl);
                pbh[(quad*4 + r) * PSTRIDE + tt*16 + m16] = ph;
                pbl[(quad*4 + r) * PSTRIDE + tt*16 + m16] = pl;
            }
        __syncthreads();
        bf16x8 aph[2], apl[2];
        #pragma unroll
        for (int kc = 0; kc < 2; kc++){
            aph[kc] = *(const bf16x8*)(pbh + m16*PSTRIDE + kc*32 + quad*8);
            apl[kc] = *(const bf16x8*)(pbl + m16*PSTRIDE + kc*32 + quad*8);
        }
        #pragma unroll
        for (int j = 0; j < 8; j++){
            #pragma unroll
            for (int kc = 0; kc < 2; kc++){
                size_t vb = vbase + (size_t)(j*16 + m16) * SS + kv0 + kc*32 + quad*8;
                bf16x8 bvh = *(const bf16x8*)(Vth + vb);
                bf16x8 bvl = *(const bf16x8*)(Vtl + vb);
                o[j] = __builtin_amdgcn_mfma_f32_16x16x32_bf16(apl[kc], bvh, o[j], 0, 0, 0);
                o[j] = __builtin_amdgcn_mfma_f32_16x16x32_bf16(aph[kc], bvl, o[j], 0, 0, 0);
                o[j] = __builtin_amdgcn_mfma_f32_16x16x32_bf16(aph[kc], bvh, o[j], 0, 0, 0);
            }
        }
    }
    // final cross-lane l reduction (cols of a row live in one quad's 16 lanes)
    #pragma unroll
    for (int r = 0; r < 4; r++){
        lrun[r] += __shfl_xor(lrun[r], 1);
        lrun[r] += __shfl_xor(lrun[r], 2);
        lrun[r] += __shfl_xor(lrun[r], 4);
        lrun[r] += __shfl_xor(lrun[r], 8);
    }
    float inv[4];
    #pragma unroll
    for (int r = 0; r < 4; r++) inv[r] = 1.0f / lrun[r];
    #pragma unroll
    for (int j = 0; j < 8; j++)
        #pragma unroll
        for (int r = 0; r < 4; r++){
            int q = q0 + quad*4 + r;
            size_t idx = ((size_t)(b*SS + q)) * 2048 + h*HD + j*16 + m16;
            u16 hh, ll;
            split2(o[j][r] * inv[r], hh, ll);
            ctxh[idx] = hh; ctxl[idx] = ll;
        }
}

// ---------------- router: fp32 logits + top2 ----------------
__global__ void k_router(const float* __restrict__ H2F, const float* __restrict__ RW,
                         int* __restrict__ topki, float* __restrict__ topkw){
    int t = blockIdx.x * 4 + (threadIdx.x >> 6);
    int lane = threadIdx.x & 63;
    const float* hr = H2F + (size_t)t * EMB;
    float acc[NEXP];
    #pragma unroll
    for (int e = 0; e < NEXP; e++) acc[e] = 0.f;
    for (int d = lane; d < EMB; d += 64){
        float hv = hr[d];
        #pragma unroll
        for (int e = 0; e < NEXP; e++) acc[e] += hv * RW[e*EMB + d];
    }
    #pragma unroll
    for (int e = 0; e < NEXP; e++)
        #pragma unroll
        for (int m = 32; m; m >>= 1) acc[e] += __shfl_xor(acc[e], m);
    if (lane == 0){
        int i0 = 0; float l0 = acc[0];
        #pragma unroll
        for (int e = 1; e < NEXP; e++) if (acc[e] > l0){ l0 = acc[e]; i0 = e; }
        int i1 = -1; float l1 = -3e38f;
        #pragma unroll
        for (int e = 0; e < NEXP; e++) if (e != i0 && acc[e] > l1){ l1 = acc[e]; i1 = e; }
        float e1 = __expf(l1 - l0);
        float w0 = 1.f / (1.f + e1);
        topki[t*2] = i0; topki[t*2+1] = i1;
        topkw[t*2] = w0; topkw[t*2+1] = 1.f - w0;
    }
}

// ---------------- histogram + prefix + cursor init ----------------
__global__ void k_offsets(const int* __restrict__ topki, int* __restrict__ offs,
                          int* __restrict__ cursor){
    __shared__ int cnt[NEXP];
    if (threadIdx.x < NEXP) cnt[threadIdx.x] = 0;
    __syncthreads();
    for (int i = threadIdx.x; i < TT*2; i += blockDim.x) atomicAdd(&cnt[topki[i]], 1);
    __syncthreads();
    if (threadIdx.x == 0){
        int o = 0;
        for (int e = 0; e < NEXP; e++){ offs[e] = o; cursor[e] = o; o += cnt[e]; }
        offs[NEXP] = o;
    }
}

__global__ void k_scatter(const int* __restrict__ topki, int* __restrict__ cursor,
                          int* __restrict__ list, int* __restrict__ rowof){
    int i = blockIdx.x * blockDim.x + threadIdx.x;
    if (i < TT*2){
        int e = topki[i];
        int pos = atomicAdd(&cursor[e], 1);
        list[pos] = i >> 1;
        rowof[i] = pos;
    }
}

// ---------------- silu(gate)*up ----------------
__global__ void k_act(const u16* __restrict__ GU, u16* __restrict__ ACT){
    int i = (blockIdx.x * blockDim.x + threadIdx.x) * 4;
    int r = i >> 10, c = i & 1023;
    const u16* g = GU + (size_t)r * 2048 + c;
    ushort4 gv = *(const ushort4*)g;
    ushort4 uv = *(const ushort4*)(g + 1024);
    float gg, uu; ushort4 o;
    gg = b2f(gv.x); uu = b2f(uv.x); o.x = f2b(gg / (1.f + __expf(-gg)) * uu);
    gg = b2f(gv.y); uu = b2f(uv.y); o.y = f2b(gg / (1.f + __expf(-gg)) * uu);
    gg = b2f(gv.z); uu = b2f(uv.z); o.z = f2b(gg / (1.f + __expf(-gg)) * uu);
    gg = b2f(gv.w); uu = b2f(uv.w); o.w = f2b(gg / (1.f + __expf(-gg)) * uu);
    *(ushort4*)(ACT + (size_t)r * 1024 + c) = o;
}

// ---------------- final combine ----------------
__global__ void k_combine(const float* __restrict__ xattn, const u16* __restrict__ YD,
                          const int* __restrict__ rowof, const float* __restrict__ topkw,
                          float* __restrict__ out){
    int i = (blockIdx.x * blockDim.x + threadIdx.x) * 4;
    int t = i >> 10, c = i & 1023;
    int r0 = rowof[t*2], r1 = rowof[t*2+1];
    float w0 = topkw[t*2], w1 = topkw[t*2+1];
    float4 xa = *(const float4*)(xattn + i);
    ushort4 y0 = *(const ushort4*)(YD + (size_t)r0 * 1024 + c);
    ushort4 y1 = *(const ushort4*)(YD + (size_t)r1 * 1024 + c);
    float4 o;
    o.x = xa.x + w0 * b2f(y0.x) + w1 * b2f(y1.x);
    o.y = xa.y + w0 * b2f(y0.y) + w1 * b2f(y1.y);
    o.z = xa.z + w0 * b2f(y0.z) + w1 * b2f(y1.z);
    o.w = xa.w + w0 * b2f(y0.w) + w1 * b2f(y1.w);
    *(float4*)(out + i) = o;
}

// ---------------- workspace layout (bytes) ----------------
constexpr size_t OFF_WQKV_H = 0;                               // 6291456
constexpr size_t OFF_WQKV_L = OFF_WQKV_H + 6291456;
constexpr size_t OFF_WO_H   = OFF_WQKV_L + 6291456;            // 4194304
constexpr size_t OFF_WO_L   = OFF_WO_H + 4194304;
constexpr size_t OFF_WGU    = OFF_WO_L + 4194304;              // 33554432
constexpr size_t OFF_WD     = OFF_WGU + 33554432;              // 16777216
constexpr size_t OFF_H1H    = OFF_WD + 16777216;               // 8388608
constexpr size_t OFF_H1L    = OFF_H1H + 8388608;
constexpr size_t OFF_XATTN  = OFF_H1L + 8388608;               // 16777216 (fp32)
constexpr size_t OFF_H2F    = OFF_XATTN + 16777216;            // 16777216 (fp32)
constexpr size_t OFF_H2H    = OFF_H2F + 16777216;              // 8388608
constexpr size_t OFF_TOPKI  = OFF_H2H + 8388608;               // 32768
constexpr size_t OFF_TOPKW  = OFF_TOPKI + 32768;               // 32768
constexpr size_t OFF_OFFS   = OFF_TOPKW + 32768;               // 256
constexpr size_t OFF_CUR    = OFF_OFFS + 256;                  // 256
constexpr size_t OFF_LIST   = OFF_CUR + 256;                   // 32768
constexpr size_t OFF_ROWOF  = OFF_LIST + 32768;                // 32768
constexpr size_t OFF_A      = OFF_ROWOF + 32768;               // scratch region
// attention-phase tensors (region A)
constexpr size_t OFF_QKVF   = OFF_A;                           // 50331648 (fp32)
constexpr size_t OFF_QH     = OFF_QKVF + 50331648;             // 16777216
constexpr size_t OFF_QL     = OFF_QH + 16777216;
constexpr size_t OFF_KH     = OFF_QL + 16777216;               // 4194304
constexpr size_t OFF_KL     = OFF_KH + 4194304;
constexpr size_t OFF_VTH    = OFF_KL + 4194304;
constexpr size_t OFF_VTL    = OFF_VTH + 4194304;
constexpr size_t OFF_CTXH   = OFF_VTL + 4194304;               // 16777216
constexpr size_t OFF_CTXL   = OFF_CTXH + 16777216;
// MoE-phase tensors alias region A (attention tensors are dead by then)
constexpr size_t OFF_GU     = OFF_A;                           // 33554432
constexpr size_t OFF_ACT    = OFF_GU + 33554432;               // 16777216
constexpr size_t OFF_YD     = OFF_ACT + 16777216;              // 16777216

extern "C" void kernel_launch(void* const* d_in, const int* in_sizes, int n_in,
                              void* d_out, int out_size, void* d_ws, size_t ws_size,
                              hipStream_t stream){
    const float* x      = (const float*)d_in[0];
    const int*   posids = (const int*)  d_in[1];
    // d_in[2] = attn_mask (pure causal; implemented directly)
    const float* n1w = (const float*)d_in[3];
    const float* n2w = (const float*)d_in[4];
    const float* qnw = (const float*)d_in[5];
    const float* knw = (const float*)d_in[6];
    const float* qw  = (const float*)d_in[7];
    const float* kw  = (const float*)d_in[8];
    const float* vw  = (const float*)d_in[9];
    const float* ow  = (const float*)d_in[10];
    const float* rw  = (const float*)d_in[11];
    const float* guw = (const float*)d_in[12];
    const float* dww = (const float*)d_in[13];
    float* out = (float*)d_out;

    char* ws = (char*)d_ws;
    u16* wqkvh = (u16*)(ws + OFF_WQKV_H);
    u16* wqkvl = (u16*)(ws + OFF_WQKV_L);
    u16* woh   = (u16*)(ws + OFF_WO_H);
    u16* wol   = (u16*)(ws + OFF_WO_L);
    u16* wgu   = (u16*)(ws + OFF_WGU);
    u16* wd    = (u16*)(ws + OFF_WD);
    u16* h1h   = (u16*)(ws + OFF_H1H);
    u16* h1l   = (u16*)(ws + OFF_H1L);
    float* xattn = (float*)(ws + OFF_XATTN);
    float* h2f = (float*)(ws + OFF_H2F);
    u16* h2h   = (u16*)(ws + OFF_H2H);
    int* topki = (int*)(ws + OFF_TOPKI);
    float* topkw = (float*)(ws + OFF_TOPKW);
    int* offs  = (int*)(ws + OFF_OFFS);
    int* cursor = (int*)(ws + OFF_CUR);
    int* list  = (int*)(ws + OFF_LIST);
    int* rowof = (int*)(ws + OFF_ROWOF);
    float* qkvf = (float*)(ws + OFF_QKVF);
    u16* Qh = (u16*)(ws + OFF_QH); u16* Ql = (u16*)(ws + OFF_QL);
    u16* Kh = (u16*)(ws + OFF_KH); u16* Kl = (u16*)(ws + OFF_KL);
    u16* Vth = (u16*)(ws + OFF_VTH); u16* Vtl = (u16*)(ws + OFF_VTL);
    u16* ctxh = (u16*)(ws + OFF_CTXH); u16* ctxl = (u16*)(ws + OFF_CTXL);
    u16* gu  = (u16*)(ws + OFF_GU);
    u16* act = (u16*)(ws + OFF_ACT);
    u16* yd  = (u16*)(ws + OFF_YD);

    // weight converts
    k_cvt_split<<<2048, 256, 0, stream>>>(qw, wqkvh,             wqkvl,             2048*1024);
    k_cvt_split<<<512,  256, 0, stream>>>(kw, wqkvh + 2048*1024, wqkvl + 2048*1024, 512*1024);
    k_cvt_split<<<512,  256, 0, stream>>>(vw, wqkvh + 2560*1024, wqkvl + 2560*1024, 512*1024);
    k_cvt_split<<<2048, 256, 0, stream>>>(ow, woh, wol, 1024*2048);
    k_cvt<<<16384, 256, 0, stream>>>(guw, wgu, 8*2048*1024);
    k_cvt<<<8192,  256, 0, stream>>>(dww, wd,  8*1024*1024);

    // attention sub-block (split precision trunk)
    k_rmsnorm_split<<<TT, 256, 0, stream>>>(x, n1w, h1h, h1l);
    k_gemm_qkv<<<dim3(QKVN/64, TT/64), 64, 0, stream>>>(h1h, h1l, wqkvh, wqkvl, qkvf);
    k_qknorm_rope<<<TT, 256, 0, stream>>>(qkvf, qnw, knw, posids, Qh, Ql, Kh, Kl, Vth, Vtl);
    k_attn<<<dim3(SS/16, NH, BB), 64, 0, stream>>>(Qh, Ql, Kh, Kl, Vth, Vtl, ctxh, ctxl);
    k_gemm_o<<<dim3(EMB/64, TT/64), 64, 0, stream>>>(ctxh, ctxl, woh, wol, x, xattn);

    // MoE sub-block
    k_rmsnorm_dual<<<TT, 256, 0, stream>>>(xattn, n2w, h2f, h2h);
    k_router<<<TT/4, 256, 0, stream>>>(h2f, rw, topki, topkw);
    k_offsets<<<1, 256, 0, stream>>>(topki, offs, cursor);
    k_scatter<<<(TT*2)/256, 256, 0, stream>>>(topki, cursor, list, rowof);
    k_gemm_gu<<<dim3(2048/64, TT/64, NEXP), 64, 0, stream>>>(h2h, wgu, list, offs, gu);
    k_act<<<(TT*2*MOEH/4)/256, 256, 0, stream>>>(gu, act);
    k_gemm_down<<<dim3(EMB/64, TT/64, NEXP), 64, 0, stream>>>(act, wd, offs, yd);
    k_combine<<<(TT*EMB/4)/256, 256, 0, stream>>>(xattn, yd, rowof, topkw, out);
}

// Round 4
// 695.953 us; speedup vs baseline: 2.8753x; 2.8753x over previous
//
#include <hip/hip_runtime.h>

#define EMB  1024
#define NH   16
#define NKV  4
#define HD   128
#define NEXP 8
#define MOEH 1024
#define BB   2
#define SS   2048
#define TT   (BB*SS)      // 4096 tokens
#define QKVN 3072
#define ATT_SCALE 0.08838834764831845f  // 1/sqrt(128)

typedef unsigned short u16;
typedef unsigned int   u32;
typedef __bf16  bf16x8  __attribute__((ext_vector_type(8)));
typedef float   floatx4 __attribute__((ext_vector_type(4)));

__device__ __forceinline__ u16 f2b(float f){           // f32 -> bf16 RNE
    u32 u = __float_as_uint(f);
    u = u + 0x7fffu + ((u >> 16) & 1u);
    return (u16)(u >> 16);
}
__device__ __forceinline__ float b2f(u16 h){
    return __uint_as_float(((u32)h) << 16);
}
__device__ __forceinline__ void split2(float v, u16& hi, u16& lo){
    u16 h = f2b(v);
    hi = h;
    lo = f2b(v - b2f(h));
}
// async global->LDS, 16B per lane; LDS dest = wave-uniform base + lane*16
__device__ __forceinline__ void gld16(u16* lds, const u16* g){
    __builtin_amdgcn_global_load_lds((const __attribute__((address_space(1))) u16*)g,
                                     (__attribute__((address_space(3))) u16*)lds, 16, 0, 0);
}

// ---------------- weight converts ----------------
__global__ void k_cvt(const float* __restrict__ src, u16* __restrict__ dst, int n){
    int i = (blockIdx.x * blockDim.x + threadIdx.x) * 4;
    if (i < n){
        float4 v = *(const float4*)(src + i);
        ushort4 o;
        o.x = f2b(v.x); o.y = f2b(v.y); o.z = f2b(v.z); o.w = f2b(v.w);
        *(ushort4*)(dst + i) = o;
    }
}
__global__ void k_cvt_split(const float* __restrict__ src, u16* __restrict__ dh,
                            u16* __restrict__ dl, int n){
    int i = (blockIdx.x * blockDim.x + threadIdx.x) * 4;
    if (i < n){
        float4 v = *(const float4*)(src + i);
        ushort4 oh, ol;
        split2(v.x, oh.x, ol.x); split2(v.y, oh.y, ol.y);
        split2(v.z, oh.z, ol.z); split2(v.w, oh.w, ol.w);
        *(ushort4*)(dh + i) = oh;
        *(ushort4*)(dl + i) = ol;
    }
}

// ---------------- rmsnorm variants ----------------
__global__ void k_rmsnorm_split(const float* __restrict__ x, const float* __restrict__ w,
                                u16* __restrict__ oh, u16* __restrict__ ol){
    int t   = blockIdx.x;
    int tid = threadIdx.x;
    const float* xr = x + (size_t)t * EMB;
    float4 v = *(const float4*)(xr + tid * 4);
    float ss = v.x*v.x + v.y*v.y + v.z*v.z + v.w*v.w;
    #pragma unroll
    for (int m = 32; m; m >>= 1) ss += __shfl_xor(ss, m);
    __shared__ float sred[4];
    if ((tid & 63) == 0) sred[tid >> 6] = ss;
    __syncthreads();
    float tot = sred[0] + sred[1] + sred[2] + sred[3];
    float r = rsqrtf(tot * (1.0f / EMB) + 1e-6f);
    float4 wv = *(const float4*)(w + tid * 4);
    ushort4 h4, l4;
    split2(v.x * r * wv.x, h4.x, l4.x);
    split2(v.y * r * wv.y, h4.y, l4.y);
    split2(v.z * r * wv.z, h4.z, l4.z);
    split2(v.w * r * wv.w, h4.w, l4.w);
    *(ushort4*)(oh + (size_t)t * EMB + tid * 4) = h4;
    *(ushort4*)(ol + (size_t)t * EMB + tid * 4) = l4;
}

__global__ void k_rmsnorm_dual(const float* __restrict__ x, const float* __restrict__ w,
                               float* __restrict__ of, u16* __restrict__ oh){
    int t   = blockIdx.x;
    int tid = threadIdx.x;
    const float* xr = x + (size_t)t * EMB;
    float4 v = *(const float4*)(xr + tid * 4);
    float ss = v.x*v.x + v.y*v.y + v.z*v.z + v.w*v.w;
    #pragma unroll
    for (int m = 32; m; m >>= 1) ss += __shfl_xor(ss, m);
    __shared__ float sred[4];
    if ((tid & 63) == 0) sred[tid >> 6] = ss;
    __syncthreads();
    float tot = sred[0] + sred[1] + sred[2] + sred[3];
    float r = rsqrtf(tot * (1.0f / EMB) + 1e-6f);
    float4 wv = *(const float4*)(w + tid * 4);
    float4 o;
    o.x = v.x * r * wv.x; o.y = v.y * r * wv.y;
    o.z = v.z * r * wv.z; o.w = v.w * r * wv.w;
    *(float4*)(of + (size_t)t * EMB + tid * 4) = o;
    ushort4 h4;
    h4.x = f2b(o.x); h4.y = f2b(o.y); h4.z = f2b(o.z); h4.w = f2b(o.w);
    *(ushort4*)(oh + (size_t)t * EMB + tid * 4) = h4;
}

// =====================================================================
// 128x128-tile split GEMM (LDS-staged, BK=64, 4 waves, XOR chunk swizzle)
// C = A @ B^T; A=[M][K] hi/lo bf16, B=[N][K] hi/lo bf16.
// =====================================================================
__global__ __launch_bounds__(256, 2)
void k_gemm_qkv(const u16* __restrict__ Ah, const u16* __restrict__ Al,
                const u16* __restrict__ Bh, const u16* __restrict__ Bl,
                float* __restrict__ C){
    __shared__ __align__(16) u16 sAh[128*64], sAl[128*64], sBh[128*64], sBl[128*64];
    const int K = EMB, N = QKVN;
    int tid = threadIdx.x, wave = tid >> 6, lane = tid & 63;
    int m16 = lane & 15, quad = lane >> 4;
    int row0 = blockIdx.y * 128, col0 = blockIdx.x * 128;
    int wr = (wave >> 1) * 64, wc = (wave & 1) * 64;
    int srow[4], schk[4], sbase[4];
    #pragma unroll
    for (int n = 0; n < 4; n++){
        int q = wave*4 + n;
        int r = 8*q + (lane >> 3);
        srow[n] = r;
        schk[n] = (lane & 7) ^ (r & 7);
        sbase[n] = 512*q;
    }
    floatx4 acc[4][4];
    floatx4 z = {0.f,0.f,0.f,0.f};
    #pragma unroll
    for (int i=0;i<4;i++) for (int j=0;j<4;j++) acc[i][j] = z;
    #pragma unroll 1
    for (int k0 = 0; k0 < K; k0 += 64){
        __syncthreads();
        #pragma unroll
        for (int n = 0; n < 4; n++){
            size_t ga = (size_t)(row0 + srow[n]) * K + k0 + schk[n]*8;
            size_t gb = (size_t)(col0 + srow[n]) * K + k0 + schk[n]*8;
            gld16(sAh + sbase[n], Ah + ga);
            gld16(sAl + sbase[n], Al + ga);
            gld16(sBh + sbase[n], Bh + gb);
            gld16(sBl + sbase[n], Bl + gb);
        }
        __syncthreads();
        #pragma unroll
        for (int sub = 0; sub < 2; sub++){
            bf16x8 fah[4], fal[4], fbh[4], fbl[4];
            #pragma unroll
            for (int i = 0; i < 4; i++){
                int ra = wr + 16*i + m16; int pa = (sub*4+quad) ^ (ra & 7);
                fah[i] = *(const bf16x8*)(sAh + ra*64 + pa*8);
                fal[i] = *(const bf16x8*)(sAl + ra*64 + pa*8);
                int rb = wc + 16*i + m16; int pb = (sub*4+quad) ^ (rb & 7);
                fbh[i] = *(const bf16x8*)(sBh + rb*64 + pb*8);
                fbl[i] = *(const bf16x8*)(sBl + rb*64 + pb*8);
            }
            #pragma unroll
            for (int i = 0; i < 4; i++)
                #pragma unroll
                for (int j = 0; j < 4; j++){
                    acc[i][j] = __builtin_amdgcn_mfma_f32_16x16x32_bf16(fal[i], fbh[j], acc[i][j], 0, 0, 0);
                    acc[i][j] = __builtin_amdgcn_mfma_f32_16x16x32_bf16(fah[i], fbl[j], acc[i][j], 0, 0, 0);
                    acc[i][j] = __builtin_amdgcn_mfma_f32_16x16x32_bf16(fah[i], fbh[j], acc[i][j], 0, 0, 0);
                }
        }
    }
    #pragma unroll
    for (int i = 0; i < 4; i++)
        #pragma unroll
        for (int j = 0; j < 4; j++)
            #pragma unroll
            for (int r = 0; r < 4; r++){
                int row = row0 + wr + 16*i + quad*4 + r;
                int col = col0 + wc + 16*j + m16;
                C[(size_t)row * N + col] = acc[i][j][r];
            }
}

__global__ __launch_bounds__(256, 2)
void k_gemm_o(const u16* __restrict__ Ah, const u16* __restrict__ Al,
              const u16* __restrict__ Bh, const u16* __restrict__ Bl,
              const float* __restrict__ resid, float* __restrict__ C){
    __shared__ __align__(16) u16 sAh[128*64], sAl[128*64], sBh[128*64], sBl[128*64];
    const int K = 2048, N = EMB;
    int tid = threadIdx.x, wave = tid >> 6, lane = tid & 63;
    int m16 = lane & 15, quad = lane >> 4;
    int row0 = blockIdx.y * 128, col0 = blockIdx.x * 128;
    int wr = (wave >> 1) * 64, wc = (wave & 1) * 64;
    int srow[4], schk[4], sbase[4];
    #pragma unroll
    for (int n = 0; n < 4; n++){
        int q = wave*4 + n;
        int r = 8*q + (lane >> 3);
        srow[n] = r;
        schk[n] = (lane & 7) ^ (r & 7);
        sbase[n] = 512*q;
    }
    floatx4 acc[4][4];
    floatx4 z = {0.f,0.f,0.f,0.f};
    #pragma unroll
    for (int i=0;i<4;i++) for (int j=0;j<4;j++) acc[i][j] = z;
    #pragma unroll 1
    for (int k0 = 0; k0 < K; k0 += 64){
        __syncthreads();
        #pragma unroll
        for (int n = 0; n < 4; n++){
            size_t ga = (size_t)(row0 + srow[n]) * K + k0 + schk[n]*8;
            size_t gb = (size_t)(col0 + srow[n]) * K + k0 + schk[n]*8;
            gld16(sAh + sbase[n], Ah + ga);
            gld16(sAl + sbase[n], Al + ga);
            gld16(sBh + sbase[n], Bh + gb);
            gld16(sBl + sbase[n], Bl + gb);
        }
        __syncthreads();
        #pragma unroll
        for (int sub = 0; sub < 2; sub++){
            bf16x8 fah[4], fal[4], fbh[4], fbl[4];
            #pragma unroll
            for (int i = 0; i < 4; i++){
                int ra = wr + 16*i + m16; int pa = (sub*4+quad) ^ (ra & 7);
                fah[i] = *(const bf16x8*)(sAh + ra*64 + pa*8);
                fal[i] = *(const bf16x8*)(sAl + ra*64 + pa*8);
                int rb = wc + 16*i + m16; int pb = (sub*4+quad) ^ (rb & 7);
                fbh[i] = *(const bf16x8*)(sBh + rb*64 + pb*8);
                fbl[i] = *(const bf16x8*)(sBl + rb*64 + pb*8);
            }
            #pragma unroll
            for (int i = 0; i < 4; i++)
                #pragma unroll
                for (int j = 0; j < 4; j++){
                    acc[i][j] = __builtin_amdgcn_mfma_f32_16x16x32_bf16(fal[i], fbh[j], acc[i][j], 0, 0, 0);
                    acc[i][j] = __builtin_amdgcn_mfma_f32_16x16x32_bf16(fah[i], fbl[j], acc[i][j], 0, 0, 0);
                    acc[i][j] = __builtin_amdgcn_mfma_f32_16x16x32_bf16(fah[i], fbh[j], acc[i][j], 0, 0, 0);
                }
        }
    }
    #pragma unroll
    for (int i = 0; i < 4; i++)
        #pragma unroll
        for (int j = 0; j < 4; j++)
            #pragma unroll
            for (int r = 0; r < 4; r++){
                int row = row0 + wr + 16*i + quad*4 + r;
                int col = col0 + wc + 16*j + m16;
                C[(size_t)row * N + col] = acc[i][j][r] + resid[(size_t)row * N + col];
            }
}

// ---------------- plain bf16 MoE GEMMs (gathered A rows for gate_up) ----------------
__global__ __launch_bounds__(256, 2)
void k_gemm_gu(const u16* __restrict__ H2, const u16* __restrict__ WGU,
               const int* __restrict__ list, const int* __restrict__ offs,
               u16* __restrict__ GU){
    __shared__ __align__(16) u16 sA[128*64], sB[128*64];
    int e = blockIdx.z;
    int off = offs[e];
    int cnt = offs[e+1] - off;
    int row0 = blockIdx.y * 128;
    if (row0 >= cnt) return;
    int col0 = blockIdx.x * 128;
    const int K = EMB;
    int tid = threadIdx.x, wave = tid >> 6, lane = tid & 63;
    int m16 = lane & 15, quad = lane >> 4;
    int wr = (wave >> 1) * 64, wc = (wave & 1) * 64;
    const u16* Bp = WGU + (size_t)e * 2048 * EMB;
    int arow[4], brow[4], schk[4], sbase[4];
    #pragma unroll
    for (int n = 0; n < 4; n++){
        int q = wave*4 + n;
        int r = 8*q + (lane >> 3);
        int rl = row0 + r; rl = rl < cnt ? rl : cnt - 1;
        arow[n] = list[off + rl];
        brow[n] = col0 + r;
        schk[n] = (lane & 7) ^ (r & 7);
        sbase[n] = 512*q;
    }
    floatx4 acc[4][4];
    floatx4 z = {0.f,0.f,0.f,0.f};
    #pragma unroll
    for (int i=0;i<4;i++) for (int j=0;j<4;j++) acc[i][j] = z;
    #pragma unroll 1
    for (int k0 = 0; k0 < K; k0 += 64){
        __syncthreads();
        #pragma unroll
        for (int n = 0; n < 4; n++){
            gld16(sA + sbase[n], H2 + (size_t)arow[n] * EMB + k0 + schk[n]*8);
            gld16(sB + sbase[n], Bp + (size_t)brow[n] * EMB + k0 + schk[n]*8);
        }
        __syncthreads();
        #pragma unroll
        for (int sub = 0; sub < 2; sub++){
            bf16x8 fa[4], fb[4];
            #pragma unroll
            for (int i = 0; i < 4; i++){
                int ra = wr + 16*i + m16; int pa = (sub*4+quad) ^ (ra & 7);
                fa[i] = *(const bf16x8*)(sA + ra*64 + pa*8);
                int rb = wc + 16*i + m16; int pb = (sub*4+quad) ^ (rb & 7);
                fb[i] = *(const bf16x8*)(sB + rb*64 + pb*8);
            }
            #pragma unroll
            for (int i = 0; i < 4; i++)
                #pragma unroll
                for (int j = 0; j < 4; j++)
                    acc[i][j] = __builtin_amdgcn_mfma_f32_16x16x32_bf16(fa[i], fb[j], acc[i][j], 0, 0, 0);
        }
    }
    #pragma unroll
    for (int i = 0; i < 4; i++)
        #pragma unroll
        for (int j = 0; j < 4; j++)
            #pragma unroll
            for (int r = 0; r < 4; r++){
                int rl = row0 + wr + 16*i + quad*4 + r;
                if (rl < cnt){
                    int col = col0 + wc + 16*j + m16;
                    GU[(size_t)(off + rl) * 2048 + col] = f2b(acc[i][j][r]);
                }
            }
}

__global__ __launch_bounds__(256, 2)
void k_gemm_down(const u16* __restrict__ ACT, const u16* __restrict__ WD,
                 const int* __restrict__ offs, u16* __restrict__ YD){
    __shared__ __align__(16) u16 sA[128*64], sB[128*64];
    int e = blockIdx.z;
    int off = offs[e];
    int cnt = offs[e+1] - off;
    int row0 = blockIdx.y * 128;
    if (row0 >= cnt) return;
    int col0 = blockIdx.x * 128;
    const int K = MOEH;
    int tid = threadIdx.x, wave = tid >> 6, lane = tid & 63;
    int m16 = lane & 15, quad = lane >> 4;
    int wr = (wave >> 1) * 64, wc = (wave & 1) * 64;
    const u16* Bp = WD + (size_t)e * 1024 * MOEH;
    int arow[4], brow[4], schk[4], sbase[4];
    #pragma unroll
    for (int n = 0; n < 4; n++){
        int q = wave*4 + n;
        int r = 8*q + (lane >> 3);
        int rl = row0 + r; rl = rl < cnt ? rl : cnt - 1;
        arow[n] = off + rl;
        brow[n] = col0 + r;
        schk[n] = (lane & 7) ^ (r & 7);
        sbase[n] = 512*q;
    }
    floatx4 acc[4][4];
    floatx4 z = {0.f,0.f,0.f,0.f};
    #pragma unroll
    for (int i=0;i<4;i++) for (int j=0;j<4;j++) acc[i][j] = z;
    #pragma unroll 1
    for (int k0 = 0; k0 < K; k0 += 64){
        __syncthreads();
        #pragma unroll
        for (int n = 0; n < 4; n++){
            gld16(sA + sbase[n], ACT + (size_t)arow[n] * MOEH + k0 + schk[n]*8);
            gld16(sB + sbase[n], Bp + (size_t)brow[n] * MOEH + k0 + schk[n]*8);
        }
        __syncthreads();
        #pragma unroll
        for (int sub = 0; sub < 2; sub++){
            bf16x8 fa[4], fb[4];
            #pragma unroll
            for (int i = 0; i < 4; i++){
                int ra = wr + 16*i + m16; int pa = (sub*4+quad) ^ (ra & 7);
                fa[i] = *(const bf16x8*)(sA + ra*64 + pa*8);
                int rb = wc + 16*i + m16; int pb = (sub*4+quad) ^ (rb & 7);
                fb[i] = *(const bf16x8*)(sB + rb*64 + pb*8);
            }
            #pragma unroll
            for (int i = 0; i < 4; i++)
                #pragma unroll
                for (int j = 0; j < 4; j++)
                    acc[i][j] = __builtin_amdgcn_mfma_f32_16x16x32_bf16(fa[i], fb[j], acc[i][j], 0, 0, 0);
        }
    }
    #pragma unroll
    for (int i = 0; i < 4; i++)
        #pragma unroll
        for (int j = 0; j < 4; j++)
            #pragma unroll
            for (int r = 0; r < 4; r++){
                int rl = row0 + wr + 16*i + quad*4 + r;
                if (rl < cnt){
                    int col = col0 + wc + 16*j + m16;
                    YD[(size_t)(off + rl) * 1024 + col] = f2b(acc[i][j][r]);
                }
            }
}

// ---------------- per-head QK rmsnorm + RoPE (fp32 in, split out) ----------------
__global__ void k_qknorm_rope(const float* __restrict__ QKVF,
                              const float* __restrict__ qnw, const float* __restrict__ knw,
                              const int* __restrict__ posids,
                              u16* __restrict__ Qh, u16* __restrict__ Ql,
                              u16* __restrict__ Kh, u16* __restrict__ Kl,
                              u16* __restrict__ Vth, u16* __restrict__ Vtl){
    int t = blockIdx.x;
    int b = t >> 11, s = t & 2047;
    int wave = threadIdx.x >> 6, lane = threadIdx.x & 63;
    const float* row = QKVF + (size_t)t * QKVN;
    float pos = (float)posids[s];
    float invf = powf(10000.0f, -((float)lane) * (1.0f/64.0f));
    float fr = pos * invf;
    float sn, cs;
    sincosf(fr, &sn, &cs);
    for (int slot = wave; slot < 24; slot += 4){
        if (slot < 16){                                 // Q head
            const float* src = row + slot * HD;
            float x1 = src[lane], x2 = src[lane + 64];
            float ssq = x1*x1 + x2*x2;
            #pragma unroll
            for (int m = 32; m; m >>= 1) ssq += __shfl_xor(ssq, m);
            float r = rsqrtf(ssq * (1.0f/HD) + 1e-6f);
            float q1 = x1 * r * qnw[lane], q2 = x2 * r * qnw[lane + 64];
            float o1 = q1*cs - q2*sn, o2 = q2*cs + q1*sn;
            size_t base = ((size_t)(b*NH + slot) * SS + s) * HD;
            u16 h, l;
            split2(o1, h, l); Qh[base + lane] = h;      Ql[base + lane] = l;
            split2(o2, h, l); Qh[base + lane + 64] = h; Ql[base + lane + 64] = l;
        } else if (slot < 20){                          // K head
            int kh = slot - 16;
            const float* src = row + 2048 + kh * HD;
            float x1 = src[lane], x2 = src[lane + 64];
            float ssq = x1*x1 + x2*x2;
            #pragma unroll
            for (int m = 32; m; m >>= 1) ssq += __shfl_xor(ssq, m);
            float r = rsqrtf(ssq * (1.0f/HD) + 1e-6f);
            float q1 = x1 * r * knw[lane], q2 = x2 * r * knw[lane + 64];
            float o1 = q1*cs - q2*sn, o2 = q2*cs + q1*sn;
            size_t base = ((size_t)(b*NKV + kh) * SS + s) * HD;
            u16 h, l;
            split2(o1, h, l); Kh[base + lane] = h;      Kl[base + lane] = l;
            split2(o2, h, l); Kh[base + lane + 64] = h; Kl[base + lane + 64] = l;
        } else {                                        // V head, transposed split copy
            int vh = slot - 20;
            const float* src = row + 2560 + vh * HD;
            size_t base = ((size_t)(b*NKV + vh) * HD) * SS + s;
            u16 h, l;
            split2(src[lane], h, l);
            Vth[base + (size_t)lane * SS] = h; Vtl[base + (size_t)lane * SS] = l;
            split2(src[lane + 64], h, l);
            Vth[base + (size_t)(lane + 64) * SS] = h; Vtl[base + (size_t)(lane + 64) * SS] = l;
        }
    }
}

// =====================================================================
// flash attention v3: 4-wave blocks (64 Q rows), LDS-staged K/V via
// global_load_lds, XOR chunk swizzle, fixed-max softmax, XCD-group grid.
// =====================================================================
#define KT 32
__global__ __launch_bounds__(256, 2)
void k_attn(const u16* __restrict__ Qh, const u16* __restrict__ Ql,
            const u16* __restrict__ Kh, const u16* __restrict__ Kl,
            const u16* __restrict__ Vth, const u16* __restrict__ Vtl,
            u16* __restrict__ ctxh, u16* __restrict__ ctxl){
    // id%8 -> (b,kvh) group so each XCD's L2 holds one 2MB KV set
    int id = blockIdx.x;
    int g = id & 7;
    int b = g >> 2, kvh = g & 3;
    int w = id >> 3;
    int h = kvh * 4 + (w & 3);
    int qt = 31 - (w >> 2);              // heavy blocks dispatched first
    int q0b = qt * 64;
    int wave = threadIdx.x >> 6, lane = threadIdx.x & 63;
    int m16 = lane & 15, quad = lane >> 4;
    int q0 = q0b + wave * 16;
    size_t qbase = ((size_t)(b*NH + h) * SS + q0) * HD;
    size_t kbase = ((size_t)(b*NKV + kvh) * SS) * HD;
    size_t vbase = ((size_t)(b*NKV + kvh) * HD) * SS;

    __shared__ __align__(16) u16 sKh[KT*HD], sKl[KT*HD];   // [32][128], swizzled
    __shared__ __align__(16) u16 sVh[64*64], sVl[64*64];   // [64][64]: (d&63, halves in chunks)
    __shared__ __align__(16) u16 sPh[4*16*40], sPl[4*16*40];

    bf16x8 aqh[4], aql[4];
    #pragma unroll
    for (int kk = 0; kk < 4; kk++){
        aqh[kk] = *(const bf16x8*)(Qh + qbase + (size_t)m16 * HD + kk*32 + quad*8);
        aql[kk] = *(const bf16x8*)(Ql + qbase + (size_t)m16 * HD + kk*32 + quad*8);
    }

    // staging lane constants
    int krow[2], kchk[2], kbse[2];   // K tile: 2 instrs/wave/plane, 4 rows each
    int vrow[2], vd[2], vs[2], vbse[2]; // V tile: 2 instrs/wave/plane, 8 rows each
    #pragma unroll
    for (int n = 0; n < 2; n++){
        int q = wave*2 + n;
        int r = 4*q + (lane >> 4);
        int s = lane & 15;
        krow[n] = r;
        kchk[n] = (s & 8) | ((s ^ r) & 7);
        kbse[n] = 512*q;
        int rv = 8*q + (lane >> 3);
        int sv = lane & 7;
        int cid = sv ^ (rv & 7);
        vrow[n] = rv;
        vd[n] = rv + 64*(cid >> 2);
        vs[n] = (cid & 3) * 8;
        vbse[n] = 512*q;
    }

    floatx4 z = {0.f,0.f,0.f,0.f};
    floatx4 o[8];
    #pragma unroll
    for (int j = 0; j < 8; j++) o[j] = z;
    float lrun[4] = {0.f, 0.f, 0.f, 0.f};

    int wave_qmax = q0 + 15;
    int kv_end = q0b + 64;
    #pragma unroll 1
    for (int kv0 = 0; kv0 < kv_end; kv0 += KT){
        __syncthreads();   // previous iteration's LDS reads complete
        #pragma unroll
        for (int n = 0; n < 2; n++){
            size_t gk = kbase + (size_t)(kv0 + krow[n]) * HD + kchk[n]*8;
            gld16(sKh + kbse[n], Kh + gk);
            gld16(sKl + kbse[n], Kl + gk);
            size_t gv = vbase + (size_t)vd[n] * SS + kv0 + vs[n];
            gld16(sVh + vbse[n], Vth + gv);
            gld16(sVl + vbse[n], Vtl + gv);
        }
        __syncthreads();   // staging complete (drains vmcnt)
        if (kv0 <= wave_qmax){
            // QK^T: two 16-col tiles
            floatx4 sc[2];
            #pragma unroll
            for (int tt = 0; tt < 2; tt++){
                sc[tt] = z;
                int kr = tt*16 + m16;
                #pragma unroll
                for (int kk = 0; kk < 4; kk++){
                    int ch = kk*4 + quad;
                    int pos = (ch & 8) | ((ch ^ kr) & 7);
                    bf16x8 bkh = *(const bf16x8*)(sKh + kr*128 + pos*8);
                    bf16x8 bkl = *(const bf16x8*)(sKl + kr*128 + pos*8);
                    sc[tt] = __builtin_amdgcn_mfma_f32_16x16x32_bf16(aql[kk], bkh, sc[tt], 0, 0, 0);
                    sc[tt] = __builtin_amdgcn_mfma_f32_16x16x32_bf16(aqh[kk], bkl, sc[tt], 0, 0, 0);
                    sc[tt] = __builtin_amdgcn_mfma_f32_16x16x32_bf16(aqh[kk], bkh, sc[tt], 0, 0, 0);
                }
            }
            // fixed-max softmax (|s|<=11.32<12): p = exp(s*scale - 12)
            #pragma unroll
            for (int tt = 0; tt < 2; tt++){
                int col = kv0 + tt*16 + m16;
                #pragma unroll
                for (int r = 0; r < 4; r++){
                    int qpos = q0 + quad*4 + r;
                    float p = (col > qpos) ? 0.0f : __expf(sc[tt][r] * ATT_SCALE - 12.0f);
                    sc[tt][r] = p;
                    lrun[r] += p;
                }
            }
            // P -> per-wave LDS (C-layout -> A-layout), split
            u16* ph = sPh + wave*640;
            u16* pl = sPl + wave*640;
            #pragma unroll
            for (int tt = 0; tt < 2; tt++)
                #pragma unroll
                for (int r = 0; r < 4; r++){
                    u16 hh, ll;
                    split2(sc[tt][r], hh, ll);
                    ph[(quad*4 + r)*40 + tt*16 + m16] = hh;
                    pl[(quad*4 + r)*40 + tt*16 + m16] = ll;
                }
            bf16x8 aph = *(const bf16x8*)(ph + m16*40 + quad*8);
            bf16x8 apl = *(const bf16x8*)(pl + m16*40 + quad*8);
            // PV
            #pragma unroll
            for (int j = 0; j < 8; j++){
                int d = j*16 + m16;
                int vr = d & 63;
                int ch = quad + 4*(d >> 6);
                int pos = ch ^ (vr & 7);
                bf16x8 bvh = *(const bf16x8*)(sVh + vr*64 + pos*8);
                bf16x8 bvl = *(const bf16x8*)(sVl + vr*64 + pos*8);
                o[j] = __builtin_amdgcn_mfma_f32_16x16x32_bf16(apl, bvh, o[j], 0, 0, 0);
                o[j] = __builtin_amdgcn_mfma_f32_16x16x32_bf16(aph, bvl, o[j], 0, 0, 0);
                o[j] = __builtin_amdgcn_mfma_f32_16x16x32_bf16(aph, bvh, o[j], 0, 0, 0);
            }
        }
    }
    #pragma unroll
    for (int r = 0; r < 4; r++){
        lrun[r] += __shfl_xor(lrun[r], 1);
        lrun[r] += __shfl_xor(lrun[r], 2);
        lrun[r] += __shfl_xor(lrun[r], 4);
        lrun[r] += __shfl_xor(lrun[r], 8);
    }
    float inv[4];
    #pragma unroll
    for (int r = 0; r < 4; r++) inv[r] = 1.0f / lrun[r];
    #pragma unroll
    for (int j = 0; j < 8; j++)
        #pragma unroll
        for (int r = 0; r < 4; r++){
            int q = q0 + quad*4 + r;
            size_t idx = ((size_t)(b*SS + q)) * 2048 + h*HD + j*16 + m16;
            u16 hh, ll;
            split2(o[j][r] * inv[r], hh, ll);
            ctxh[idx] = hh; ctxl[idx] = ll;
        }
}

// ---------------- router: fp32 logits + top2 ----------------
__global__ void k_router(const float* __restrict__ H2F, const float* __restrict__ RW,
                         int* __restrict__ topki, float* __restrict__ topkw){
    int t = blockIdx.x * 4 + (threadIdx.x >> 6);
    int lane = threadIdx.x & 63;
    const float* hr = H2F + (size_t)t * EMB;
    float acc[NEXP];
    #pragma unroll
    for (int e = 0; e < NEXP; e++) acc[e] = 0.f;
    for (int d = lane; d < EMB; d += 64){
        float hv = hr[d];
        #pragma unroll
        for (int e = 0; e < NEXP; e++) acc[e] += hv * RW[e*EMB + d];
    }
    #pragma unroll
    for (int e = 0; e < NEXP; e++)
        #pragma unroll
        for (int m = 32; m; m >>= 1) acc[e] += __shfl_xor(acc[e], m);
    if (lane == 0){
        int i0 = 0; float l0 = acc[0];
        #pragma unroll
        for (int e = 1; e < NEXP; e++) if (acc[e] > l0){ l0 = acc[e]; i0 = e; }
        int i1 = -1; float l1 = -3e38f;
        #pragma unroll
        for (int e = 0; e < NEXP; e++) if (e != i0 && acc[e] > l1){ l1 = acc[e]; i1 = e; }
        float e1 = __expf(l1 - l0);
        float w0 = 1.f / (1.f + e1);
        topki[t*2] = i0; topki[t*2+1] = i1;
        topkw[t*2] = w0; topkw[t*2+1] = 1.f - w0;
    }
}

// ---------------- histogram + prefix + cursor init ----------------
__global__ void k_offsets(const int* __restrict__ topki, int* __restrict__ offs,
                          int* __restrict__ cursor){
    __shared__ int cnt[NEXP];
    if (threadIdx.x < NEXP) cnt[threadIdx.x] = 0;
    __syncthreads();
    for (int i = threadIdx.x; i < TT*2; i += blockDim.x) atomicAdd(&cnt[topki[i]], 1);
    __syncthreads();
    if (threadIdx.x == 0){
        int o = 0;
        for (int e = 0; e < NEXP; e++){ offs[e] = o; cursor[e] = o; o += cnt[e]; }
        offs[NEXP] = o;
    }
}

__global__ void k_scatter(const int* __restrict__ topki, int* __restrict__ cursor,
                          int* __restrict__ list, int* __restrict__ rowof){
    int i = blockIdx.x * blockDim.x + threadIdx.x;
    if (i < TT*2){
        int e = topki[i];
        int pos = atomicAdd(&cursor[e], 1);
        list[pos] = i >> 1;
        rowof[i] = pos;
    }
}

// ---------------- silu(gate)*up ----------------
__global__ void k_act(const u16* __restrict__ GU, u16* __restrict__ ACT){
    int i = (blockIdx.x * blockDim.x + threadIdx.x) * 4;
    int r = i >> 10, c = i & 1023;
    const u16* g = GU + (size_t)r * 2048 + c;
    ushort4 gv = *(const ushort4*)g;
    ushort4 uv = *(const ushort4*)(g + 1024);
    float gg, uu; ushort4 o;
    gg = b2f(gv.x); uu = b2f(uv.x); o.x = f2b(gg / (1.f + __expf(-gg)) * uu);
    gg = b2f(gv.y); uu = b2f(uv.y); o.y = f2b(gg / (1.f + __expf(-gg)) * uu);
    gg = b2f(gv.z); uu = b2f(uv.z); o.z = f2b(gg / (1.f + __expf(-gg)) * uu);
    gg = b2f(gv.w); uu = b2f(uv.w); o.w = f2b(gg / (1.f + __expf(-gg)) * uu);
    *(ushort4*)(ACT + (size_t)r * 1024 + c) = o;
}

// ---------------- final combine ----------------
__global__ void k_combine(const float* __restrict__ xattn, const u16* __restrict__ YD,
                          const int* __restrict__ rowof, const float* __restrict__ topkw,
                          float* __restrict__ out){
    int i = (blockIdx.x * blockDim.x + threadIdx.x) * 4;
    int t = i >> 10, c = i & 1023;
    int r0 = rowof[t*2], r1 = rowof[t*2+1];
    float w0 = topkw[t*2], w1 = topkw[t*2+1];
    float4 xa = *(const float4*)(xattn + i);
    ushort4 y0 = *(const ushort4*)(YD + (size_t)r0 * 1024 + c);
    ushort4 y1 = *(const ushort4*)(YD + (size_t)r1 * 1024 + c);
    float4 o;
    o.x = xa.x + w0 * b2f(y0.x) + w1 * b2f(y1.x);
    o.y = xa.y + w0 * b2f(y0.y) + w1 * b2f(y1.y);
    o.z = xa.z + w0 * b2f(y0.z) + w1 * b2f(y1.z);
    o.w = xa.w + w0 * b2f(y0.w) + w1 * b2f(y1.w);
    *(float4*)(out + i) = o;
}

// ---------------- workspace layout (bytes) ----------------
constexpr size_t OFF_WQKV_H = 0;                               // 6291456
constexpr size_t OFF_WQKV_L = OFF_WQKV_H + 6291456;
constexpr size_t OFF_WO_H   = OFF_WQKV_L + 6291456;            // 4194304
constexpr size_t OFF_WO_L   = OFF_WO_H + 4194304;
constexpr size_t OFF_WGU    = OFF_WO_L + 4194304;              // 33554432
constexpr size_t OFF_WD     = OFF_WGU + 33554432;              // 16777216
constexpr size_t OFF_H1H    = OFF_WD + 16777216;               // 8388608
constexpr size_t OFF_H1L    = OFF_H1H + 8388608;
constexpr size_t OFF_XATTN  = OFF_H1L + 8388608;               // 16777216 (fp32)
constexpr size_t OFF_H2F    = OFF_XATTN + 16777216;            // 16777216 (fp32)
constexpr size_t OFF_H2H    = OFF_H2F + 16777216;              // 8388608
constexpr size_t OFF_TOPKI  = OFF_H2H + 8388608;               // 32768
constexpr size_t OFF_TOPKW  = OFF_TOPKI + 32768;               // 32768
constexpr size_t OFF_OFFS   = OFF_TOPKW + 32768;               // 256
constexpr size_t OFF_CUR    = OFF_OFFS + 256;                  // 256
constexpr size_t OFF_LIST   = OFF_CUR + 256;                   // 32768
constexpr size_t OFF_ROWOF  = OFF_LIST + 32768;                // 32768
constexpr size_t OFF_A      = OFF_ROWOF + 32768;               // scratch region
// attention-phase tensors (region A)
constexpr size_t OFF_QKVF   = OFF_A;                           // 50331648 (fp32)
constexpr size_t OFF_QH     = OFF_QKVF + 50331648;             // 16777216
constexpr size_t OFF_QL     = OFF_QH + 16777216;
constexpr size_t OFF_KH     = OFF_QL + 16777216;               // 4194304
constexpr size_t OFF_KL     = OFF_KH + 4194304;
constexpr size_t OFF_VTH    = OFF_KL + 4194304;
constexpr size_t OFF_VTL    = OFF_VTH + 4194304;
constexpr size_t OFF_CTXH   = OFF_VTL + 4194304;               // 16777216
constexpr size_t OFF_CTXL   = OFF_CTXH + 16777216;
// MoE-phase tensors alias region A (attention tensors are dead by then)
constexpr size_t OFF_GU     = OFF_A;                           // 33554432
constexpr size_t OFF_ACT    = OFF_GU + 33554432;               // 16777216
constexpr size_t OFF_YD     = OFF_ACT + 16777216;              // 16777216

extern "C" void kernel_launch(void* const* d_in, const int* in_sizes, int n_in,
                              void* d_out, int out_size, void* d_ws, size_t ws_size,
                              hipStream_t stream){
    const float* x      = (const float*)d_in[0];
    const int*   posids = (const int*)  d_in[1];
    // d_in[2] = attn_mask (pure causal; implemented directly)
    const float* n1w = (const float*)d_in[3];
    const float* n2w = (const float*)d_in[4];
    const float* qnw = (const float*)d_in[5];
    const float* knw = (const float*)d_in[6];
    const float* qw  = (const float*)d_in[7];
    const float* kw  = (const float*)d_in[8];
    const float* vw  = (const float*)d_in[9];
    const float* ow  = (const float*)d_in[10];
    const float* rw  = (const float*)d_in[11];
    const float* guw = (const float*)d_in[12];
    const float* dww = (const float*)d_in[13];
    float* out = (float*)d_out;

    char* ws = (char*)d_ws;
    u16* wqkvh = (u16*)(ws + OFF_WQKV_H);
    u16* wqkvl = (u16*)(ws + OFF_WQKV_L);
    u16* woh   = (u16*)(ws + OFF_WO_H);
    u16* wol   = (u16*)(ws + OFF_WO_L);
    u16* wgu   = (u16*)(ws + OFF_WGU);
    u16* wd    = (u16*)(ws + OFF_WD);
    u16* h1h   = (u16*)(ws + OFF_H1H);
    u16* h1l   = (u16*)(ws + OFF_H1L);
    float* xattn = (float*)(ws + OFF_XATTN);
    float* h2f = (float*)(ws + OFF_H2F);
    u16* h2h   = (u16*)(ws + OFF_H2H);
    int* topki = (int*)(ws + OFF_TOPKI);
    float* topkw = (float*)(ws + OFF_TOPKW);
    int* offs  = (int*)(ws + OFF_OFFS);
    int* cursor = (int*)(ws + OFF_CUR);
    int* list  = (int*)(ws + OFF_LIST);
    int* rowof = (int*)(ws + OFF_ROWOF);
    float* qkvf = (float*)(ws + OFF_QKVF);
    u16* Qh = (u16*)(ws + OFF_QH); u16* Ql = (u16*)(ws + OFF_QL);
    u16* Kh = (u16*)(ws + OFF_KH); u16* Kl = (u16*)(ws + OFF_KL);
    u16* Vth = (u16*)(ws + OFF_VTH); u16* Vtl = (u16*)(ws + OFF_VTL);
    u16* ctxh = (u16*)(ws + OFF_CTXH); u16* ctxl = (u16*)(ws + OFF_CTXL);
    u16* gu  = (u16*)(ws + OFF_GU);
    u16* act = (u16*)(ws + OFF_ACT);
    u16* yd  = (u16*)(ws + OFF_YD);

    // weight converts
    k_cvt_split<<<2048, 256, 0, stream>>>(qw, wqkvh,             wqkvl,             2048*1024);
    k_cvt_split<<<512,  256, 0, stream>>>(kw, wqkvh + 2048*1024, wqkvl + 2048*1024, 512*1024);
    k_cvt_split<<<512,  256, 0, stream>>>(vw, wqkvh + 2560*1024, wqkvl + 2560*1024, 512*1024);
    k_cvt_split<<<2048, 256, 0, stream>>>(ow, woh, wol, 1024*2048);
    k_cvt<<<16384, 256, 0, stream>>>(guw, wgu, 8*2048*1024);
    k_cvt<<<8192,  256, 0, stream>>>(dww, wd,  8*1024*1024);

    // attention sub-block (split precision trunk)
    k_rmsnorm_split<<<TT, 256, 0, stream>>>(x, n1w, h1h, h1l);
    k_gemm_qkv<<<dim3(QKVN/128, TT/128), 256, 0, stream>>>(h1h, h1l, wqkvh, wqkvl, qkvf);
    k_qknorm_rope<<<TT, 256, 0, stream>>>(qkvf, qnw, knw, posids, Qh, Ql, Kh, Kl, Vth, Vtl);
    k_attn<<<1024, 256, 0, stream>>>(Qh, Ql, Kh, Kl, Vth, Vtl, ctxh, ctxl);
    k_gemm_o<<<dim3(EMB/128, TT/128), 256, 0, stream>>>(ctxh, ctxl, woh, wol, x, xattn);

    // MoE sub-block
    k_rmsnorm_dual<<<TT, 256, 0, stream>>>(xattn, n2w, h2f, h2h);
    k_router<<<TT/4, 256, 0, stream>>>(h2f, rw, topki, topkw);
    k_offsets<<<1, 256, 0, stream>>>(topki, offs, cursor);
    k_scatter<<<(TT*2)/256, 256, 0, stream>>>(topki, cursor, list, rowof);
    k_gemm_gu<<<dim3(2048/128, TT/128, NEXP), 256, 0, stream>>>(h2h, wgu, list, offs, gu);
    k_act<<<(TT*2*MOEH/4)/256, 256, 0, stream>>>(gu, act);
    k_gemm_down<<<dim3(EMB/128, TT/128, NEXP), 256, 0, stream>>>(act, wd, offs, yd);
    k_combine<<<(TT*EMB/4)/256, 256, 0, stream>>>(xattn, yd, rowof, topkw, out);
}